// Round 2
// baseline (278.255 us; speedup 1.0000x reference)
//
#include <hip/hip_runtime.h>

#define BN 4
#define EN 32
#define NPIX (512 * 512)   // 262144 = 2^18
#define CSEG 2048
#define NEDGE 8192

#define DELTA_VAR 0.1f
#define DELTA_DIST 0.3f

// ---- partial-sum accumulate geometry (no global atomics) ----
#define ECHUNK 4
#define NECH (EN / ECHUNK)            // 8
#define ATHREADS 512

// -------- kernel 1a: LDS-aggregated partial segment sums (plain-store flush) --------
__global__ __launch_bounds__(ATHREADS) void rag_accum_part(
    const float* __restrict__ emb, const int* __restrict__ seg,
    float* __restrict__ partial, float* __restrict__ cpart, int pixblk) {
  __shared__ float lsum[ECHUNK * CSEG];  // 32 KB
  __shared__ float lcnt[CSEG];           // 8 KB (ech==0 blocks only)

  const int blk = blockIdx.x;  // grid = BN * NECH * pixblk
  const int pb = blk % pixblk;
  const int ech = (blk / pixblk) % NECH;
  const int b = blk / (pixblk * NECH);

  for (int i = threadIdx.x; i < ECHUNK * CSEG; i += ATHREADS) lsum[i] = 0.0f;
  if (ech == 0)
    for (int i = threadIdx.x; i < CSEG; i += ATHREADS) lcnt[i] = 0.0f;
  __syncthreads();

  const int ppb = NPIX / pixblk;
  const int p0 = pb * ppb;
  const float* __restrict__ eb = emb + ((size_t)b * EN + (size_t)ech * ECHUNK) * NPIX;
  const int* __restrict__ sb = seg + (size_t)b * NPIX;

  for (int p = p0 + threadIdx.x; p < p0 + ppb; p += ATHREADS) {
    const int s = sb[p];
    if (ech == 0) atomicAdd(&lcnt[s], 1.0f);
#pragma unroll
    for (int e = 0; e < ECHUNK; e++) {
      atomicAdd(&lsum[e * CSEG + s], eb[(size_t)e * NPIX + p]);
    }
  }
  __syncthreads();

  // flush: disjoint per-block region, plain coalesced stores
  float* __restrict__ gp = partial + (size_t)blk * (ECHUNK * CSEG);
  for (int i = threadIdx.x; i < ECHUNK * CSEG; i += ATHREADS) gp[i] = lsum[i];
  if (ech == 0) {
    float* __restrict__ cp = cpart + ((size_t)b * pixblk + pb) * CSEG;
    for (int i = threadIdx.x; i < CSEG; i += ATHREADS) cp[i] = lcnt[i];
  }
}

// -------- kernel 1b: reduce partials over pb --------
__global__ __launch_bounds__(256) void rag_reduce(
    const float* __restrict__ partial, const float* __restrict__ cpart,
    float* __restrict__ sums, float* __restrict__ counts, int pixblk) {
  const int idx = blockIdx.x * 256 + threadIdx.x;  // over B*EN*CSEG
  if (idx >= BN * EN * CSEG) return;
  const int c = idx & (CSEG - 1);
  const int e = (idx >> 11) & (EN - 1);
  const int b = idx >> 16;  // EN*CSEG = 65536
  const int ech = e >> 2;   // / ECHUNK
  const int el = e & 3;
  const float* __restrict__ p =
      partial + ((size_t)((b * NECH + ech) * pixblk) * ECHUNK + el) * CSEG + c;
  float s = 0.0f;
#pragma unroll 8
  for (int pb = 0; pb < pixblk; pb++) s += p[(size_t)pb * ECHUNK * CSEG];
  sums[idx] = s;
  if (e == 0) {  // wave-uniform (CSEG multiple of 64)
    const float* __restrict__ cp = cpart + (size_t)b * pixblk * CSEG + c;
    float cs = 0.0f;
#pragma unroll 8
    for (int pb = 0; pb < pixblk; pb++) cs += cp[(size_t)pb * CSEG];
    counts[b * CSEG + c] = cs;
  }
}

// -------- fallback kernel (small ws): LDS-aggregated + global-atomic flush --------
#define FECHUNK 8
#define FNECH (EN / FECHUNK)   // 4
#define FPIXBLK 32
#define FPPB (NPIX / FPIXBLK)  // 8192
__global__ __launch_bounds__(ATHREADS) void rag_accum_atomic(
    const float* __restrict__ emb, const int* __restrict__ seg,
    float* __restrict__ counts, float* __restrict__ sums) {
  __shared__ float lsum[FECHUNK * CSEG];
  __shared__ float lcnt[CSEG];
  const int blk = blockIdx.x;
  const int pb = blk % FPIXBLK;
  const int ech = (blk / FPIXBLK) % FNECH;
  const int b = blk / (FPIXBLK * FNECH);
  for (int i = threadIdx.x; i < FECHUNK * CSEG; i += ATHREADS) lsum[i] = 0.0f;
  if (ech == 0)
    for (int i = threadIdx.x; i < CSEG; i += ATHREADS) lcnt[i] = 0.0f;
  __syncthreads();
  const int p0 = pb * FPPB;
  const float* __restrict__ eb = emb + ((size_t)b * EN + (size_t)ech * FECHUNK) * NPIX;
  const int* __restrict__ sb = seg + (size_t)b * NPIX;
  for (int p = p0 + threadIdx.x; p < p0 + FPPB; p += ATHREADS) {
    const int s = sb[p];
    if (ech == 0) atomicAdd(&lcnt[s], 1.0f);
#pragma unroll
    for (int e = 0; e < FECHUNK; e++)
      atomicAdd(&lsum[e * CSEG + s], eb[(size_t)e * NPIX + p]);
  }
  __syncthreads();
  float* __restrict__ gs = sums + (size_t)b * EN * CSEG;
  for (int i = threadIdx.x; i < FECHUNK * CSEG; i += ATHREADS) {
    const float v = lsum[i];
    if (v != 0.0f) {
      const int e = i / CSEG;
      const int c = i - e * CSEG;
      atomicAdd(&gs[(size_t)(ech * FECHUNK + e) * CSEG + c], v);
    }
  }
  if (ech == 0) {
    float* __restrict__ gc = counts + (size_t)b * CSEG;
    for (int i = threadIdx.x; i < CSEG; i += ATHREADS) {
      const float v = lcnt[i];
      if (v != 0.0f) atomicAdd(&gc[i], v);
    }
  }
}

// -------- kernel 2: means = normalize(sums / max(count,1)); transpose to [B][C][E] --------
__global__ __launch_bounds__(256) void rag_finalize(
    const float* __restrict__ counts, const float* __restrict__ sums,
    float* __restrict__ means) {
  const int idx = blockIdx.x * 256 + threadIdx.x;
  if (idx >= BN * CSEG) return;
  const int b = idx / CSEG;
  const int c = idx - b * CSEG;
  const float inv = 1.0f / fmaxf(counts[idx], 1.0f);
  const float* __restrict__ sbase = sums + (size_t)b * EN * CSEG + c;
  float m[EN];
  float nrm = 0.0f;
#pragma unroll
  for (int e = 0; e < EN; e++) {
    const float v = sbase[(size_t)e * CSEG] * inv;
    m[e] = v;
    nrm += v * v;
  }
  const float s = 1.0f / fmaxf(sqrtf(nrm), 1e-10f);
  float* __restrict__ mb = means + (size_t)idx * EN;
#pragma unroll
  for (int e = 0; e < EN; e++) mb[e] = m[e] * s;
}

// -------- kernel 3: intra loss (second streaming pass over embeddings) --------
#define ITHREADS 256
__global__ __launch_bounds__(ITHREADS) void rag_intra(
    const float* __restrict__ emb, const int* __restrict__ seg,
    const float* __restrict__ counts, const float* __restrict__ means,
    float* __restrict__ out) {
  float acc = 0.0f;
  const int total = BN * NPIX;
  for (int i = blockIdx.x * ITHREADS + threadIdx.x; i < total;
       i += gridDim.x * ITHREADS) {
    const int b = i >> 18;
    const int p = i & (NPIX - 1);
    const int s = seg[i];
    const float4* __restrict__ mv =
        (const float4*)(means + ((size_t)b * CSEG + s) * EN);
    const float* __restrict__ eb = emb + (size_t)b * EN * NPIX + p;
    float dot = 0.0f;
#pragma unroll
    for (int e4 = 0; e4 < EN / 4; e4++) {
      const float4 m4 = mv[e4];
      dot += m4.x * eb[(size_t)(e4 * 4 + 0) * NPIX];
      dot += m4.y * eb[(size_t)(e4 * 4 + 1) * NPIX];
      dot += m4.z * eb[(size_t)(e4 * 4 + 2) * NPIX];
      dot += m4.w * eb[(size_t)(e4 * 4 + 3) * NPIX];
    }
    const float d = 1.0f - dot - DELTA_VAR;
    if (d > 0.0f) acc += d / counts[b * CSEG + s];
  }
  for (int o = 32; o > 0; o >>= 1) acc += __shfl_down(acc, o, 64);
  __shared__ float wsum[ITHREADS / 64];
  const int lane = threadIdx.x & 63;
  const int wid = threadIdx.x >> 6;
  if (lane == 0) wsum[wid] = acc;
  __syncthreads();
  if (threadIdx.x == 0) {
    float bsum = 0.0f;
#pragma unroll
    for (int w = 0; w < ITHREADS / 64; w++) bsum += wsum[w];
    atomicAdd(out, bsum * (1.0f / CSEG));
  }
}

// -------- kernel 4: inter loss over RAG edges --------
#define JTHREADS 256
__global__ __launch_bounds__(JTHREADS) void rag_inter(
    const int* __restrict__ edges, const float* __restrict__ weights,
    const float* __restrict__ means, float* __restrict__ out) {
  const int idx = blockIdx.x * JTHREADS + threadIdx.x;
  float val = 0.0f;
  if (idx < BN * NEDGE) {
    const int b = idx >> 13;
    const int k = idx & (NEDGE - 1);
    const int e0 = edges[(size_t)b * 2 * NEDGE + k];
    const int e1 = edges[(size_t)b * 2 * NEDGE + NEDGE + k];
    const float w = weights[idx];
    const float4* __restrict__ m0 =
        (const float4*)(means + ((size_t)b * CSEG + e0) * EN);
    const float4* __restrict__ m1 =
        (const float4*)(means + ((size_t)b * CSEG + e1) * EN);
    float dot = 0.0f;
#pragma unroll
    for (int e4 = 0; e4 < EN / 4; e4++) {
      const float4 a = m0[e4];
      const float4 c = m1[e4];
      dot += a.x * c.x + a.y * c.y + a.z * c.z + a.w * c.w;
    }
    val = fmaxf(DELTA_DIST - (1.0f - dot) * w, 0.0f);
  }
  for (int o = 32; o > 0; o >>= 1) val += __shfl_down(val, o, 64);
  __shared__ float wsum[JTHREADS / 64];
  const int lane = threadIdx.x & 63;
  const int wid = threadIdx.x >> 6;
  if (lane == 0) wsum[wid] = val;
  __syncthreads();
  if (threadIdx.x == 0) {
    float bsum = 0.0f;
#pragma unroll
    for (int w = 0; w < JTHREADS / 64; w++) bsum += wsum[w];
    atomicAdd(out, bsum * (1.0f / NEDGE));
  }
}

extern "C" void kernel_launch(void* const* d_in, const int* in_sizes, int n_in,
                              void* d_out, int out_size, void* d_ws, size_t ws_size,
                              hipStream_t stream) {
  const float* emb = (const float*)d_in[0];     // [B][E][H][W]
  const int* seg = (const int*)d_in[1];         // [B][1][H][W]
  const int* edges = (const int*)d_in[2];       // [B][2][NEDGE]
  const float* weights = (const float*)d_in[3]; // [B][NEDGE]
  float* out = (float*)d_out;
  float* ws = (float*)d_ws;

  hipMemsetAsync(d_out, 0, (size_t)out_size * sizeof(float), stream);

  // fixed tail: sums [B][E][C], counts [B][C], means [B][C][E]
  const size_t FIXED = (size_t)BN * EN * CSEG + BN * CSEG + (size_t)BN * CSEG * EN;
  const size_t ws_floats = ws_size / sizeof(float);

  int pixblk = 0;
  {
    const int cands[3] = {32, 16, 8};
    for (int k = 0; k < 3; k++) {
      const size_t part = (size_t)BN * EN * CSEG * cands[k];   // partial sums
      const size_t cprt = (size_t)BN * cands[k] * CSEG;        // partial counts
      if (part + cprt + FIXED <= ws_floats) { pixblk = cands[k]; break; }
    }
  }

  float *sums, *counts, *means;
  if (pixblk > 0) {
    float* partial = ws;
    float* cpart = partial + (size_t)BN * EN * CSEG * pixblk;
    sums = cpart + (size_t)BN * pixblk * CSEG;
    counts = sums + (size_t)BN * EN * CSEG;
    means = counts + (size_t)BN * CSEG;

    rag_accum_part<<<BN * NECH * pixblk, ATHREADS, 0, stream>>>(
        emb, seg, partial, cpart, pixblk);
    rag_reduce<<<(BN * EN * CSEG + 255) / 256, 256, 0, stream>>>(
        partial, cpart, sums, counts, pixblk);
  } else {
    // fallback: atomic flush into zeroed accumulators
    counts = ws;
    sums = counts + (size_t)BN * CSEG;
    means = sums + (size_t)BN * EN * CSEG;
    hipMemsetAsync(ws, 0, ((size_t)BN * CSEG + (size_t)BN * EN * CSEG) * sizeof(float), stream);
    rag_accum_atomic<<<BN * FNECH * FPIXBLK, ATHREADS, 0, stream>>>(emb, seg, counts, sums);
  }

  rag_finalize<<<(BN * CSEG + 255) / 256, 256, 0, stream>>>(counts, sums, means);
  rag_intra<<<1024, ITHREADS, 0, stream>>>(emb, seg, counts, means, out);
  rag_inter<<<(BN * NEDGE + JTHREADS - 1) / JTHREADS, JTHREADS, 0, stream>>>(
      edges, weights, means, out);
}